// Round 1
// baseline (47.395 us; speedup 1.0000x reference)
//
#include <hip/hip_runtime.h>

#define F 32
#define Dd 16
#define C 64
#define Kk 8
#define CLIPV (1.0f - 1e-6f)
#define ROWSTRIDE 264  // ushorts per LDS basis row: 256 data + 8 pad = 528B, 16B-aligned

typedef short v4s __attribute__((ext_vector_type(4)));
typedef float v4f __attribute__((ext_vector_type(4)));

static __device__ inline unsigned short f2bf(float f) {
    // round-to-nearest-even float32 -> bf16
    unsigned u = __builtin_bit_cast(unsigned, f);
    unsigned r = u + 0x7FFFu + ((u >> 16) & 1u);
    return (unsigned short)(r >> 16);
}

static __device__ inline unsigned pk2(float lo, float hi) {
    return (unsigned)f2bf(lo) | ((unsigned)f2bf(hi) << 16);
}

__global__ __launch_bounds__(256, 4) void qkan_kernel(
    const float* __restrict__ X,        // [B,32]
    const float* __restrict__ phases,   // [16]
    const float* __restrict__ lcu_w,    // [32,16]
    const float* __restrict__ sscale,   // [32]
    const float* __restrict__ sbias,    // [32]
    const float* __restrict__ coeff,    // [64,32,8]
    const float* __restrict__ kbias,    // [64]
    float* __restrict__ out)            // [B,64]
{
    __shared__ unsigned short s_basis[64 * ROWSTRIDE];  // 33792 B
    __shared__ float2 s_ab[F][Dd];                      // 4096 B
    __shared__ float s_fb[F];                           // 128 B

    const int tid = threadIdx.x;
    const int lane = tid & 63;
    const int w = tid >> 6;  // wave id 0..3

    // ---- block init: folded QSVT/LCU coefficient table ----
    for (int idx = tid; idx < F * Dd; idx += 256) {
        const int f = idx >> 4, d = idx & 15;
        float asum = 0.f;
#pragma unroll
        for (int dd = 0; dd < Dd; ++dd) asum += fabsf(lcu_w[f * Dd + dd]);
        const float sc = sscale[f] / (asum + 1e-6f);
        float sp, cp;
        sincosf(phases[d], &sp, &cp);
        const float wv = lcu_w[f * Dd + d];
        s_ab[f][d] = make_float2(sc * wv * cp, -sc * wv * sp);
        if (d == 0) s_fb[f] = sbias[f];
    }

    // ---- per-wave B fragments (this wave's 16 classes), bf16, MFMA layout ----
    // B[k_local][n]: lane holds B[4*(lane/16)+e][lane%16] for kstep q:
    // global GEMM-k kappa = 16q + 4h + e, with kappa = (fl*4 + chunk)*8 + k,
    // f = chunk*8 + fl  (permuted K-order matching the LDS basis layout)
    v4s Bfr[16];
    {
        const int h = lane >> 4;
        const int cidx = w * 16 + (lane & 15);
        const int kb = 4 * (h & 1);
#pragma unroll
        for (int q = 0; q < 16; ++q) {
            const int m2 = 2 * q + (h >> 1);
            const int f = (m2 & 3) * 8 + (m2 >> 2);
            const float4 g = *reinterpret_cast<const float4*>(coeff + ((cidx * F + f) * Kk + kb));
            v4s b;
            b[0] = (short)f2bf(g.x);
            b[1] = (short)f2bf(g.y);
            b[2] = (short)f2bf(g.z);
            b[3] = (short)f2bf(g.w);
            Bfr[q] = b;
        }
    }
    const float biasreg = kbias[w * 16 + (lane & 15)];

    __syncthreads();

    for (int mt = 0; mt < 4; ++mt) {
        const int row_base = (blockIdx.x * 4 + mt) * 64;

        // ---- phase 1: features + Chebyshev basis -> LDS (wave w does f in [8w,8w+8) for all 64 rows) ----
        {
            const float* xr = X + (size_t)(row_base + lane) * F + w * 8;
            const float4 xa = *reinterpret_cast<const float4*>(xr);
            const float4 xb = *reinterpret_cast<const float4*>(xr + 4);
            const float xv[8] = {xa.x, xa.y, xa.z, xa.w, xb.x, xb.y, xb.z, xb.w};
#pragma unroll
            for (int fl = 0; fl < 8; ++fl) {
                const int f = w * 8 + fl;
                const float x = fminf(fmaxf(xv[fl], -CLIPV), CLIPV);
                const float c1 = x;
                const float s1 = sqrtf(fmaxf(1.f - x * x, 0.f));
                float ck = c1, sk = s1;
                float2 ab = s_ab[f][0];
                float z = ab.x * ck + ab.y * sk;
#pragma unroll
                for (int d = 1; d < Dd; ++d) {
                    const float cn = ck * c1 - sk * s1;
                    const float sn = sk * c1 + ck * s1;
                    ck = cn; sk = sn;
                    const float2 abd = s_ab[f][d];
                    z += abd.x * ck + abd.y * sk;
                }
                z += s_fb[f];
                // tanh via exp
                const float e2 = __expf(2.f * z);
                float tt = __fdividef(e2 - 1.f, e2 + 1.f);
                tt = fminf(fmaxf(tt, -CLIPV), CLIPV);
                // Chebyshev basis T_0..T_7
                const float t2 = 2.f * tt;
                const float b0 = 1.f, b1 = tt;
                const float b2 = t2 * b1 - b0;
                const float b3 = t2 * b2 - b1;
                const float b4 = t2 * b3 - b2;
                const float b5 = t2 * b4 - b3;
                const float b6 = t2 * b5 - b4;
                const float b7 = t2 * b6 - b5;
                uint4 pk;
                pk.x = pk2(b0, b1);
                pk.y = pk2(b2, b3);
                pk.z = pk2(b4, b5);
                pk.w = pk2(b6, b7);
                *reinterpret_cast<uint4*>(&s_basis[lane * ROWSTRIDE + (fl * 4 + w) * 8]) = pk;
            }
        }
        __syncthreads();

        // ---- phase 2: MFMA GEMM, wave w computes classes [16w,16w+16) for all 64 rows ----
        {
            const int r16 = lane & 15;
            const int hq = lane >> 4;
            const int col = w * 16 + r16;
#pragma unroll
            for (int t = 0; t < 4; ++t) {
                v4f acc = {0.f, 0.f, 0.f, 0.f};
                const unsigned short* ap =
                    &s_basis[(t * 16 + r16) * ROWSTRIDE + (hq >> 1) * 8 + (hq & 1) * 4];
#pragma unroll
                for (int q = 0; q < 16; ++q) {
                    const v4s a = *reinterpret_cast<const v4s*>(ap + q * 16);
                    acc = __builtin_amdgcn_mfma_f32_16x16x16bf16_1k(a, Bfr[q], acc, 0, 0, 0);
                }
                const int row0 = row_base + t * 16 + hq * 4;
#pragma unroll
                for (int i = 0; i < 4; ++i) {
                    out[(size_t)(row0 + i) * C + col] = acc[i] + biasreg;
                }
            }
        }
        __syncthreads();
    }
}

extern "C" void kernel_launch(void* const* d_in, const int* in_sizes, int n_in,
                              void* d_out, int out_size, void* d_ws, size_t ws_size,
                              hipStream_t stream) {
    const float* X  = (const float*)d_in[0];
    const float* ph = (const float*)d_in[1];
    const float* lw = (const float*)d_in[2];
    const float* ss = (const float*)d_in[3];
    const float* sb = (const float*)d_in[4];
    const float* kc = (const float*)d_in[5];
    const float* kb = (const float*)d_in[6];
    float* out = (float*)d_out;
    qkan_kernel<<<dim3(512), dim3(256), 0, stream>>>(X, ph, lw, ss, sb, kc, kb, out);
}

// Round 2
// 36.482 us; speedup vs baseline: 1.2991x; 1.2991x over previous
//
#include <hip/hip_runtime.h>

#define F 32
#define Dd 16
#define C 64
#define Kk 8
#define CLIPV (1.0f - 1e-6f)
#define CHUNKB 1040   // bytes per k-chunk: 64 rows * 16B + 16B pad (odd # of 16B slots)
#define CHUNKS (CHUNKB / 2)
#define TAB_FLOATS 1056   // 32*16*2 table + 32 bias
#define TAB_BYTES (TAB_FLOATS * 4)
#define NBLK 2048

typedef short v4s __attribute__((ext_vector_type(4)));
typedef float v4f __attribute__((ext_vector_type(4)));

static __device__ inline unsigned cvtpk(float lo, float hi) {
    unsigned r;
    asm("v_cvt_pk_bf16_f32 %0, %1, %2" : "=v"(r) : "v"(lo), "v"(hi));
    return r;
}

// Fold qsvt_phases + lcu_weights + sum_scale into per-(f,d) (a,b):
//   z_f = sum_d a_fd*cos(d theta) + b_fd*sin(d theta);  plus bias fb.
__global__ void qkan_prep(const float* __restrict__ phases,
                          const float* __restrict__ lcu_w,
                          const float* __restrict__ sscale,
                          const float* __restrict__ sbias,
                          float* __restrict__ ws) {
    const int idx = threadIdx.x;  // 512 threads, one (f,d) each
    if (idx < F * Dd) {
        const int f = idx >> 4, d = idx & 15;
        float asum = 0.f;
        for (int dd = 0; dd < Dd; ++dd) asum += fabsf(lcu_w[f * Dd + dd]);
        const float sc = sscale[f] / (asum + 1e-6f);
        float sp, cp;
        sincosf(phases[d], &sp, &cp);
        const float wv = lcu_w[f * Dd + d];
        ws[2 * idx]     = sc * wv * cp;
        ws[2 * idx + 1] = -sc * wv * sp;
        if (d == 0) ws[1024 + f] = sbias[f];
    }
}

template <bool WS>
__global__ __launch_bounds__(256, 4) void qkan_kernel(
    const float* __restrict__ X,        // [B,32]
    const float* __restrict__ phases,   // [16]
    const float* __restrict__ lcu_w,    // [32,16]
    const float* __restrict__ sscale,   // [32]
    const float* __restrict__ sbias,    // [32]
    const float* __restrict__ coeff,    // [64,32,8]
    const float* __restrict__ kbias,    // [64]
    const float* __restrict__ tab,      // folded table in d_ws (WS path)
    float* __restrict__ out)            // [B,64]
{
    // chunk-major basis: chunk c (=feature f) holds 64 rows x 8 bf16 (16B/row)
    __shared__ unsigned short s_basis[F * CHUNKS];       // 33280 B
    __shared__ float s_tab[WS ? 4 : TAB_FLOATS];         // fallback-only table

    const int tid = threadIdx.x;
    const int lane = tid & 63;
    const int wu = __builtin_amdgcn_readfirstlane(tid >> 6);  // wave id, uniform
    const int h = lane >> 4;
    const int r16 = lane & 15;

    if (!WS) {
        for (int idx = tid; idx < F * Dd; idx += 256) {
            const int f = idx >> 4, d = idx & 15;
            float asum = 0.f;
#pragma unroll
            for (int dd = 0; dd < Dd; ++dd) asum += fabsf(lcu_w[f * Dd + dd]);
            const float sc = sscale[f] / (asum + 1e-6f);
            float sp, cp;
            sincosf(phases[d], &sp, &cp);
            const float wv = lcu_w[f * Dd + d];
            s_tab[2 * idx]     = sc * wv * cp;
            s_tab[2 * idx + 1] = -sc * wv * sp;
            if (d == 0) s_tab[1024 + f] = sbias[f];
        }
        __syncthreads();
    }

    // ---- B fragments: wave wu owns classes [16wu,16wu+16) ----
    // step q: lane (h) holds kappa_phys = (2q + (h>>1))*8 + (h&1)*4 + e,
    // i.e. f = 2q + (h>>1), cheb-k = (h&1)*4 + e
    v4s Bfr[16];
    {
        const int cidx = wu * 16 + r16;
#pragma unroll
        for (int q = 0; q < 16; ++q) {
            const int f = 2 * q + (h >> 1);
            const float4 g =
                *reinterpret_cast<const float4*>(coeff + ((cidx * F + f) * Kk + (h & 1) * 4));
            union { unsigned u[2]; v4s v; } bb;
            bb.u[0] = cvtpk(g.x, g.y);
            bb.u[1] = cvtpk(g.z, g.w);
            Bfr[q] = bb.v;
        }
    }
    const float biasreg = kbias[wu * 16 + r16];

    const int row_base = blockIdx.x * 64;

    // ---- phase 1: lane owns row (row_base+lane), wave owns features [8wu,8wu+8) ----
    {
        const float* xr = X + (size_t)(row_base + lane) * F + wu * 8;
        const float4 xa = *reinterpret_cast<const float4*>(xr);
        const float4 xb = *reinterpret_cast<const float4*>(xr + 4);
        const float xv[8] = {xa.x, xa.y, xa.z, xa.w, xb.x, xb.y, xb.z, xb.w};
#pragma unroll
        for (int fl = 0; fl < 8; ++fl) {
            const int f = wu * 8 + fl;
            const float* tf = WS ? (tab + f * 32) : (s_tab + f * 32);
            const float fb = WS ? tab[1024 + f] : s_tab[1024 + f];
            const float x = fminf(fmaxf(xv[fl], -CLIPV), CLIPV);
            const float c1 = x;
            const float s1 = sqrtf(fmaxf(1.f - x * x, 0.f));
            float ck = c1, sk = s1;
            float z = tf[0] * c1 + tf[1] * s1;
#pragma unroll
            for (int d = 1; d < Dd; ++d) {
                const float t1 = sk * s1;
                const float cn = __builtin_fmaf(ck, c1, -t1);
                const float t2_ = ck * s1;
                const float sn = __builtin_fmaf(sk, c1, t2_);
                ck = cn;
                sk = sn;
                z = __builtin_fmaf(tf[2 * d], ck, z);
                z = __builtin_fmaf(tf[2 * d + 1], sk, z);
            }
            z += fb;
            // tanh(z) = 1 - 2/(exp(2z)+1)
            const float e2 = __expf(2.f * z);
            const float rr = __builtin_amdgcn_rcpf(e2 + 1.f);
            float t = __builtin_fmaf(-2.f, rr, 1.f);
            t = fminf(fmaxf(t, -CLIPV), CLIPV);
            // Chebyshev basis T_0..T_7
            const float t2 = 2.f * t;
            const float b1 = t;
            const float b2 = t2 * b1 - 1.f;
            const float b3 = t2 * b2 - b1;
            const float b4 = t2 * b3 - b2;
            const float b5 = t2 * b4 - b3;
            const float b6 = t2 * b5 - b4;
            const float b7 = t2 * b6 - b5;
            uint4 pk;
            pk.x = cvtpk(1.f, b1);
            pk.y = cvtpk(b2, b3);
            pk.z = cvtpk(b4, b5);
            pk.w = cvtpk(b6, b7);
            // conflict-free: 64 lanes write contiguous 1024B within chunk f
            *reinterpret_cast<uint4*>(&s_basis[f * CHUNKS + lane * 8]) = pk;
        }
    }
    __syncthreads();

    // ---- phase 2: MFMA, wave wu computes classes [16wu,16wu+16) for 64 rows ----
    {
        const int col = wu * 16 + r16;
#pragma unroll
        for (int t = 0; t < 4; ++t) {
            v4f acc = {0.f, 0.f, 0.f, 0.f};
#pragma unroll
            for (int q = 0; q < 16; ++q) {
                const int c = 2 * q + (h >> 1);
                const v4s a = *reinterpret_cast<const v4s*>(
                    &s_basis[c * CHUNKS + (t * 16 + r16) * 8 + (h & 1) * 4]);
                acc = __builtin_amdgcn_mfma_f32_16x16x16bf16_1k(a, Bfr[q], acc, 0, 0, 0);
            }
            const int row0 = row_base + t * 16 + h * 4;
#pragma unroll
            for (int i = 0; i < 4; ++i) {
                out[(size_t)(row0 + i) * C + col] = acc[i] + biasreg;
            }
        }
    }
}

extern "C" void kernel_launch(void* const* d_in, const int* in_sizes, int n_in,
                              void* d_out, int out_size, void* d_ws, size_t ws_size,
                              hipStream_t stream) {
    const float* X  = (const float*)d_in[0];
    const float* ph = (const float*)d_in[1];
    const float* lw = (const float*)d_in[2];
    const float* ss = (const float*)d_in[3];
    const float* sb = (const float*)d_in[4];
    const float* kc = (const float*)d_in[5];
    const float* kb = (const float*)d_in[6];
    float* out = (float*)d_out;

    if (d_ws != nullptr && ws_size >= (size_t)TAB_BYTES) {
        float* ws = (float*)d_ws;
        qkan_prep<<<dim3(1), dim3(512), 0, stream>>>(ph, lw, ss, sb, ws);
        qkan_kernel<true><<<dim3(NBLK), dim3(256), 0, stream>>>(
            X, ph, lw, ss, sb, kc, kb, (const float*)ws, out);
    } else {
        qkan_kernel<false><<<dim3(NBLK), dim3(256), 0, stream>>>(
            X, ph, lw, ss, sb, kc, kb, nullptr, out);
    }
}

// Round 3
// 35.448 us; speedup vs baseline: 1.3370x; 1.0292x over previous
//
#include <hip/hip_runtime.h>

#define F 32
#define Dd 16
#define C 64
#define Kk 8
#define CLIPV (1.0f - 1e-6f)
#define CHUNKS 512        // ushorts per k-chunk: 64 rows * 8 bf16 (16B/row), 1024B
#define TABSTRIDE 36      // floats per feature: 16 a + 16 b + bias + pad
#define TAB_FLOATS (F * TABSTRIDE)
#define TAB_BYTES (TAB_FLOATS * 4)
#define NBLK 2048

typedef short v8s __attribute__((ext_vector_type(8)));
typedef float v4f __attribute__((ext_vector_type(4)));

static __device__ inline unsigned cvtpk(float lo, float hi) {
    unsigned r;
    asm("v_cvt_pk_bf16_f32 %0, %1, %2" : "=v"(r) : "v"(lo), "v"(hi));
    return r;
}

// Fold phases/lcu_weights/sum_scale into per-f Clenshaw tables:
//   z_f(x) = sum_d a_fd T_d(x) + sqrt(1-x^2) * sum_d b_fd U_{d-1}(x) + bias_f
// layout ws[f*36 + {0..15:a_d, 16..31:b_d, 32:bias}]
__global__ void qkan_prep(const float* __restrict__ phases,
                          const float* __restrict__ lcu_w,
                          const float* __restrict__ sscale,
                          const float* __restrict__ sbias,
                          float* __restrict__ ws) {
    const int idx = threadIdx.x;  // 512 threads, one (f,d) each
    if (idx < F * Dd) {
        const int f = idx >> 4, d = idx & 15;
        float asum = 0.f;
        for (int dd = 0; dd < Dd; ++dd) asum += fabsf(lcu_w[f * Dd + dd]);
        const float sc = sscale[f] / (asum + 1e-6f);
        float sp, cp;
        sincosf(phases[d], &sp, &cp);
        const float wv = lcu_w[f * Dd + d];
        ws[f * TABSTRIDE + d]      = sc * wv * cp;   // a_{d+1}
        ws[f * TABSTRIDE + 16 + d] = -sc * wv * sp;  // b_{d+1}
        if (d == 0) ws[f * TABSTRIDE + 32] = sbias[f];
    }
}

template <bool WS>
__global__ __launch_bounds__(256, 4) void qkan_kernel(
    const float* __restrict__ X,        // [B,32]
    const float* __restrict__ phases,   // [16]
    const float* __restrict__ lcu_w,    // [32,16]
    const float* __restrict__ sscale,   // [32]
    const float* __restrict__ sbias,    // [32]
    const float* __restrict__ coeff,    // [64,32,8]
    const float* __restrict__ kbias,    // [64]
    const float* __restrict__ tab,      // folded table in d_ws (WS path)
    float* __restrict__ out)            // [B,64]
{
    // chunk-major basis: chunk f holds 64 rows x 8 bf16 (16B/row), contiguous 1KB
    __shared__ unsigned short s_basis[F * CHUNKS];   // 32768 B
    __shared__ float s_tab[WS ? 4 : TAB_FLOATS];     // fallback-only table

    const int tid = threadIdx.x;
    const int lane = tid & 63;
    const int wu = __builtin_amdgcn_readfirstlane(tid >> 6);  // wave id, uniform
    const int h = lane >> 4;
    const int r16 = lane & 15;

    if (!WS) {
        for (int idx = tid; idx < F * Dd; idx += 256) {
            const int f = idx >> 4, d = idx & 15;
            float asum = 0.f;
#pragma unroll
            for (int dd = 0; dd < Dd; ++dd) asum += fabsf(lcu_w[f * Dd + dd]);
            const float sc = sscale[f] / (asum + 1e-6f);
            float sp, cp;
            sincosf(phases[d], &sp, &cp);
            const float wv = lcu_w[f * Dd + d];
            s_tab[f * TABSTRIDE + d]      = sc * wv * cp;
            s_tab[f * TABSTRIDE + 16 + d] = -sc * wv * sp;
            if (d == 0) s_tab[f * TABSTRIDE + 32] = sbias[f];
        }
        __syncthreads();
    }

    const int row_base = blockIdx.x * 64;

    // ---- phase 1: lane owns row (row_base+lane), wave owns features [8wu,8wu+8) ----
    {
        const float* xr = X + (size_t)(row_base + lane) * F + wu * 8;
        const float4 xa = *reinterpret_cast<const float4*>(xr);
        const float4 xb = *reinterpret_cast<const float4*>(xr + 4);
        const float xv[8] = {xa.x, xa.y, xa.z, xa.w, xb.x, xb.y, xb.z, xb.w};
#pragma unroll
        for (int fl = 0; fl < 8; ++fl) {
            const int f = wu * 8 + fl;
            const float* tf = WS ? (tab + f * TABSTRIDE) : (s_tab + f * TABSTRIDE);
            const float x = fminf(fmaxf(xv[fl], -CLIPV), CLIPV);
            const float s1 = sqrtf(fmaxf(__builtin_fmaf(-x, x, 1.f), 0.f));
            const float tx = x + x;
            // Clenshaw: sum_d a_d T_d(x), d=16..1
            float u1 = 0.f, u2 = 0.f;
#pragma unroll
            for (int d = 16; d >= 1; --d) {
                const float un = __builtin_fmaf(tx, u1, tf[d - 1] - u2);
                u2 = u1; u1 = un;
            }
            // Clenshaw: sum_m b_{m+1} U_m(x), m=15..0
            float v1 = 0.f, v2 = 0.f;
#pragma unroll
            for (int m = 15; m >= 0; --m) {
                const float vn = __builtin_fmaf(tx, v1, tf[16 + m] - v2);
                v2 = v1; v1 = vn;
            }
            const float fb = tf[32];
            float z = __builtin_fmaf(x, u1, fb - u2);
            z = __builtin_fmaf(s1, v1, z);
            // tanh(z) = 1 - 2/(exp(2z)+1)
            const float e2 = __expf(2.f * z);
            const float rr = __builtin_amdgcn_rcpf(e2 + 1.f);
            float t = __builtin_fmaf(-2.f, rr, 1.f);
            t = fminf(fmaxf(t, -CLIPV), CLIPV);
            // Chebyshev basis T_0..T_7
            const float t2 = 2.f * t;
            const float b1 = t;
            const float b2 = t2 * b1 - 1.f;
            const float b3 = t2 * b2 - b1;
            const float b4 = t2 * b3 - b2;
            const float b5 = t2 * b4 - b3;
            const float b6 = t2 * b5 - b4;
            const float b7 = t2 * b6 - b5;
            uint4 pk;
            pk.x = cvtpk(1.f, b1);
            pk.y = cvtpk(b2, b3);
            pk.z = cvtpk(b4, b5);
            pk.w = cvtpk(b6, b7);
            // conflict-free: 64 lanes write contiguous 1024B within chunk f
            *reinterpret_cast<uint4*>(&s_basis[f * CHUNKS + lane * 8]) = pk;
        }
    }

    // ---- B fragments (loaded AFTER phase 1 to keep phase-1 VGPR pressure low) ----
    // MFMA step q, lane quarter h, regs j=0..7 hold phys kappa = (4q+h)*8 + j,
    // i.e. f = 4q+h, cheb-k = j (same lane<->k map on A and B => K-perm invariant)
    v8s Bfr[8];
    const int cidx = wu * 16 + r16;
#pragma unroll
    for (int q = 0; q < 8; ++q) {
        const int f = 4 * q + h;
        const float* gp = coeff + ((size_t)(cidx * F + f) * Kk);
        const float4 g0 = *reinterpret_cast<const float4*>(gp);
        const float4 g1 = *reinterpret_cast<const float4*>(gp + 4);
        union { unsigned u[4]; v8s v; } bb;
        bb.u[0] = cvtpk(g0.x, g0.y);
        bb.u[1] = cvtpk(g0.z, g0.w);
        bb.u[2] = cvtpk(g1.x, g1.y);
        bb.u[3] = cvtpk(g1.z, g1.w);
        Bfr[q] = bb.v;
    }
    const float biasreg = kbias[cidx];

    __syncthreads();

    // ---- phase 2: MFMA, wave wu computes classes [16wu,16wu+16) for 64 rows ----
    {
#pragma unroll
        for (int t = 0; t < 4; ++t) {
            v4f acc = {0.f, 0.f, 0.f, 0.f};
#pragma unroll
            for (int q = 0; q < 8; ++q) {
                const v8s a = *reinterpret_cast<const v8s*>(
                    &s_basis[(4 * q + h) * CHUNKS + (t * 16 + r16) * 8]);
                acc = __builtin_amdgcn_mfma_f32_16x16x32_bf16(a, Bfr[q], acc, 0, 0, 0);
            }
            const int row0 = row_base + t * 16 + h * 4;
#pragma unroll
            for (int i = 0; i < 4; ++i) {
                out[(size_t)(row0 + i) * C + cidx] = acc[i] + biasreg;
            }
        }
    }
}

extern "C" void kernel_launch(void* const* d_in, const int* in_sizes, int n_in,
                              void* d_out, int out_size, void* d_ws, size_t ws_size,
                              hipStream_t stream) {
    const float* X  = (const float*)d_in[0];
    const float* ph = (const float*)d_in[1];
    const float* lw = (const float*)d_in[2];
    const float* ss = (const float*)d_in[3];
    const float* sb = (const float*)d_in[4];
    const float* kc = (const float*)d_in[5];
    const float* kb = (const float*)d_in[6];
    float* out = (float*)d_out;

    if (d_ws != nullptr && ws_size >= (size_t)TAB_BYTES) {
        float* ws = (float*)d_ws;
        qkan_prep<<<dim3(1), dim3(512), 0, stream>>>(ph, lw, ss, sb, ws);
        qkan_kernel<true><<<dim3(NBLK), dim3(256), 0, stream>>>(
            X, ph, lw, ss, sb, kc, kb, (const float*)ws, out);
    } else {
        qkan_kernel<false><<<dim3(NBLK), dim3(256), 0, stream>>>(
            X, ph, lw, ss, sb, kc, kb, nullptr, out);
    }
}

// Round 4
// 30.519 us; speedup vs baseline: 1.5530x; 1.1615x over previous
//
#include <hip/hip_runtime.h>

#define F 32
#define Dd 16
#define C 64
#define Kk 8
#define CLIPV (1.0f - 1e-6f)
#define CHUNKS 528        // ushorts per k-chunk: 64 rows * 8 bf16 + 32B pad -> 1056B (mod 128 = 32)
#define TABSTRIDE 36      // floats per feature: 16 (a,b) pairs + bias + pad
#define TAB_FLOATS (F * TABSTRIDE)
#define TAB_BYTES (TAB_FLOATS * 4)
#define NBLK 1024
#define MT 2              // row-tiles of 64 per block
#define K2 2.8853900817779268f  // 2*log2(e): tanh(z)=1-2/(2^(K2*z)+1)

typedef short v8s __attribute__((ext_vector_type(8)));
typedef float v4f __attribute__((ext_vector_type(4)));
typedef float v2f __attribute__((ext_vector_type(2)));

static __device__ inline unsigned cvtpk(float lo, float hi) {
    unsigned r;
    asm("v_cvt_pk_bf16_f32 %0, %1, %2" : "=v"(r) : "v"(lo), "v"(hi));
    return r;
}

// Fold phases/lcu_weights/sum_scale (and the 2*log2e tanh prescale) into
// per-f Clenshaw tables: K2*z_f(x) = sum_d a_fd T_d(x) + sqrt(1-x^2)*sum b U + fb
// layout ws[f*36 + {2d: a_{d+1}, 2d+1: b_{d+1}, 32: fb}]
__global__ void qkan_prep(const float* __restrict__ phases,
                          const float* __restrict__ lcu_w,
                          const float* __restrict__ sscale,
                          const float* __restrict__ sbias,
                          float* __restrict__ ws) {
    const int idx = threadIdx.x;  // 512 threads, one (f,d) each
    if (idx < F * Dd) {
        const int f = idx >> 4, d = idx & 15;
        float asum = 0.f;
        for (int dd = 0; dd < Dd; ++dd) asum += fabsf(lcu_w[f * Dd + dd]);
        const float sc = K2 * sscale[f] / (asum + 1e-6f);
        float sp, cp;
        sincosf(phases[d], &sp, &cp);
        const float wv = lcu_w[f * Dd + d];
        ws[f * TABSTRIDE + 2 * d]     = sc * wv * cp;   // a_{d+1}
        ws[f * TABSTRIDE + 2 * d + 1] = -sc * wv * sp;  // b_{d+1}
        if (d == 0) ws[f * TABSTRIDE + 32] = K2 * sbias[f];
    }
}

template <bool WS>
__global__ __launch_bounds__(256, 4) void qkan_kernel(
    const float* __restrict__ X,        // [B,32]
    const float* __restrict__ phases,   // [16]
    const float* __restrict__ lcu_w,    // [32,16]
    const float* __restrict__ sscale,   // [32]
    const float* __restrict__ sbias,    // [32]
    const float* __restrict__ coeff,    // [64,32,8]
    const float* __restrict__ kbias,    // [64]
    const float* __restrict__ tab,      // folded table in d_ws (WS path)
    float* __restrict__ out)            // [B,64]
{
    // chunk-major basis: chunk f holds 64 rows x 8 bf16 (16B/row); stride 1056B
    // staggers chunk bases mod 128B so phase-2 quarter-wave reads are conflict-free
    __shared__ unsigned short s_basis[F * CHUNKS];   // 33792 B
    __shared__ float s_tab[WS ? 4 : TAB_FLOATS];     // fallback-only table

    const int tid = threadIdx.x;
    const int lane = tid & 63;
    const int wu = __builtin_amdgcn_readfirstlane(tid >> 6);  // wave id, uniform
    const int h = lane >> 4;
    const int r16 = lane & 15;

    if (!WS) {
        for (int idx = tid; idx < F * Dd; idx += 256) {
            const int f = idx >> 4, d = idx & 15;
            float asum = 0.f;
#pragma unroll
            for (int dd = 0; dd < Dd; ++dd) asum += fabsf(lcu_w[f * Dd + dd]);
            const float sc = K2 * sscale[f] / (asum + 1e-6f);
            float sp, cp;
            sincosf(phases[d], &sp, &cp);
            const float wv = lcu_w[f * Dd + d];
            s_tab[f * TABSTRIDE + 2 * d]     = sc * wv * cp;
            s_tab[f * TABSTRIDE + 2 * d + 1] = -sc * wv * sp;
            if (d == 0) s_tab[f * TABSTRIDE + 32] = K2 * sbias[f];
        }
        __syncthreads();
    }

    // ---- B fragments: wave wu owns classes [16wu,16wu+16) ----
    // MFMA step q, lane quarter h, regs j=0..7 hold phys kappa=(4q+h)*8+j,
    // i.e. f=4q+h, cheb-k=j (same lane<->k map on A and B => K-perm invariant)
    v8s Bfr[8];
    const int cidx = wu * 16 + r16;
#pragma unroll
    for (int q = 0; q < 8; ++q) {
        const int f = 4 * q + h;
        const float* gp = coeff + ((size_t)(cidx * F + f) * Kk);
        const float4 g0 = *reinterpret_cast<const float4*>(gp);
        const float4 g1 = *reinterpret_cast<const float4*>(gp + 4);
        union { unsigned u[4]; v8s v; } bb;
        bb.u[0] = cvtpk(g0.x, g0.y);
        bb.u[1] = cvtpk(g0.z, g0.w);
        bb.u[2] = cvtpk(g1.x, g1.y);
        bb.u[3] = cvtpk(g1.z, g1.w);
        Bfr[q] = bb.v;
    }
    const float biasreg = kbias[cidx];

    for (int mt = 0; mt < MT; ++mt) {
        const int row_base = (blockIdx.x * MT + mt) * 64;
        if (mt) __syncthreads();  // previous phase-2 reads done before overwrite

        // ---- phase 1: lane owns a row, wave owns features [8wu,8wu+8) ----
        {
            const float* xr = X + (size_t)(row_base + lane) * F + wu * 8;
            const float4 xa = *reinterpret_cast<const float4*>(xr);
            const float4 xb = *reinterpret_cast<const float4*>(xr + 4);
            const float xv[8] = {xa.x, xa.y, xa.z, xa.w, xb.x, xb.y, xb.z, xb.w};
#pragma unroll
            for (int fl = 0; fl < 8; ++fl) {
                const int f = wu * 8 + fl;
                const float* tfp = WS ? (tab + f * TABSTRIDE) : (s_tab + f * TABSTRIDE);
                const v2f* tf2 = reinterpret_cast<const v2f*>(tfp);
                const float fb = tfp[32];
                const float x = fminf(fmaxf(xv[fl], -CLIPV), CLIPV);
                const float s1 = sqrtf(fmaxf(__builtin_fmaf(-x, x, 1.f), 0.f));
                const float tx = x + x;
                const v2f tx2 = {tx, tx};
                // paired Clenshaw: .x = T-chain (coeff a), .y = U-chain (coeff b)
                v2f w = {0.f, 0.f}, wp = {0.f, 0.f};
#pragma unroll
                for (int j = 15; j >= 0; --j) {
                    const v2f wn = (tf2[j] - wp) + tx2 * w;  // v_pk_add + v_pk_fma
                    wp = w;
                    w = wn;
                }
                float z = fb - wp.x;                    // fb - u2
                z = __builtin_fmaf(x, w.x, z);          // + x*u1
                z = __builtin_fmaf(s1, w.y, z);         // + sqrt(1-x^2)*v1
                // tanh via exp2 (K2 pre-folded): t = 1 - 2/(2^z + 1)
                float e;
                asm("v_exp_f32 %0, %1" : "=v"(e) : "v"(z));
                const float rr = __builtin_amdgcn_rcpf(e + 1.f);
                const float t = __builtin_fmaf(-2.f, rr, 1.f);
                // Chebyshev basis T_0..T_7
                const float t2 = t + t;
                const float b1 = t;
                const float b2 = t2 * b1 - 1.f;
                const float b3 = t2 * b2 - b1;
                const float b4 = t2 * b3 - b2;
                const float b5 = t2 * b4 - b3;
                const float b6 = t2 * b5 - b4;
                const float b7 = t2 * b6 - b5;
                uint4 pk;
                pk.x = cvtpk(1.f, b1);
                pk.y = cvtpk(b2, b3);
                pk.z = cvtpk(b4, b5);
                pk.w = cvtpk(b6, b7);
                // conflict-free: 64 lanes write contiguous 1KB within chunk f
                *reinterpret_cast<uint4*>(&s_basis[f * CHUNKS + lane * 8]) = pk;
            }
        }
        __syncthreads();

        // ---- phase 2: MFMA, wave wu computes classes [16wu,16wu+16) for 64 rows ----
        {
#pragma unroll
            for (int t = 0; t < 4; ++t) {
                v4f acc = {0.f, 0.f, 0.f, 0.f};
#pragma unroll
                for (int q = 0; q < 8; ++q) {
                    const v8s a = *reinterpret_cast<const v8s*>(
                        &s_basis[(4 * q + h) * CHUNKS + (t * 16 + r16) * 8]);
                    acc = __builtin_amdgcn_mfma_f32_16x16x32_bf16(a, Bfr[q], acc, 0, 0, 0);
                }
                const int row0 = row_base + t * 16 + h * 4;
#pragma unroll
                for (int i = 0; i < 4; ++i) {
                    out[(size_t)(row0 + i) * C + cidx] = acc[i] + biasreg;
                }
            }
        }
    }
}

extern "C" void kernel_launch(void* const* d_in, const int* in_sizes, int n_in,
                              void* d_out, int out_size, void* d_ws, size_t ws_size,
                              hipStream_t stream) {
    const float* X  = (const float*)d_in[0];
    const float* ph = (const float*)d_in[1];
    const float* lw = (const float*)d_in[2];
    const float* ss = (const float*)d_in[3];
    const float* sb = (const float*)d_in[4];
    const float* kc = (const float*)d_in[5];
    const float* kb = (const float*)d_in[6];
    float* out = (float*)d_out;

    if (d_ws != nullptr && ws_size >= (size_t)TAB_BYTES) {
        float* ws = (float*)d_ws;
        qkan_prep<<<dim3(1), dim3(512), 0, stream>>>(ph, lw, ss, sb, ws);
        qkan_kernel<true><<<dim3(NBLK), dim3(256), 0, stream>>>(
            X, ph, lw, ss, sb, kc, kb, (const float*)ws, out);
    } else {
        qkan_kernel<false><<<dim3(NBLK), dim3(256), 0, stream>>>(
            X, ph, lw, ss, sb, kc, kb, nullptr, out);
    }
}

// Round 5
// 29.434 us; speedup vs baseline: 1.6102x; 1.0369x over previous
//
#include <hip/hip_runtime.h>

#define F 32
#define Dd 16
#define C 64
#define Kk 8
#define CLIPV (1.0f - 1e-6f)
#define CHUNKS 528        // ushorts per k-chunk: 64 rows * 8 bf16 + 32B pad -> 1056B (mod 128 = 32)
#define TABSTRIDE 36      // floats per feature: 16 (a,b) pairs + bias + pad (8B-aligned stride)
#define NBLK 1024
#define MT 2              // row-tiles of 64 per block
#define K2 2.8853900817779268f  // 2*log2(e): tanh(z)=1-2/(2^(K2*z)+1)

typedef short v8s __attribute__((ext_vector_type(8)));
typedef float v4f __attribute__((ext_vector_type(4)));
typedef float v2f __attribute__((ext_vector_type(2)));

static __device__ inline unsigned cvtpk(float lo, float hi) {
    unsigned r;
    asm("v_cvt_pk_bf16_f32 %0, %1, %2" : "=v"(r) : "v"(lo), "v"(hi));
    return r;
}

__global__ __launch_bounds__(256, 4) void qkan_kernel(
    const float* __restrict__ X,        // [B,32]
    const float* __restrict__ phases,   // [16]
    const float* __restrict__ lcu_w,    // [32,16]
    const float* __restrict__ sscale,   // [32]
    const float* __restrict__ sbias,    // [32]
    const float* __restrict__ coeff,    // [64,32,8]
    const float* __restrict__ kbias,    // [64]
    float* __restrict__ out)            // [B,64]
{
    // chunk-major basis: chunk f holds 64 rows x 8 bf16 (16B/row); stride 1056B
    // staggers chunk bases mod 128B so phase-2 quarter-wave reads are conflict-free
    __shared__ unsigned short s_basis[F * CHUNKS];   // 33792 B
    __shared__ float s_tab[F * TABSTRIDE];           // folded Clenshaw table, 4608 B

    const int tid = threadIdx.x;
    const int lane = tid & 63;
    const int wu = __builtin_amdgcn_readfirstlane(tid >> 6);  // wave id, uniform
    const int h = lane >> 4;
    const int r16 = lane & 15;

    // ---- X prefetch for BOTH row-tiles (issued before any dependent work) ----
    const int rb0 = blockIdx.x * (MT * 64);
    const float* xr0 = X + (size_t)(rb0 + lane) * F + wu * 8;
    const float4 xa0 = *reinterpret_cast<const float4*>(xr0);
    const float4 xb0 = *reinterpret_cast<const float4*>(xr0 + 4);
    const float* xr1 = xr0 + 64 * F;
    const float4 xa1 = *reinterpret_cast<const float4*>(xr1);
    const float4 xb1 = *reinterpret_cast<const float4*>(xr1 + 4);

    // ---- fold table per block (overlaps the prefetch latency above) ----
    // K2*z_f(x) = sum_d a_fd T_d(x) + sqrt(1-x^2) * sum_d b_fd U_{d-1}(x) + fb_f
    // layout s_tab[f*36 + {2d: a_{d+1}, 2d+1: b_{d+1}, 32: fb}]
    for (int idx = tid; idx < F * Dd; idx += 256) {
        const int f = idx >> 4, d = idx & 15;
        float asum = 0.f;
#pragma unroll
        for (int dd = 0; dd < Dd; ++dd) asum += fabsf(lcu_w[f * Dd + dd]);
        const float sc = K2 * sscale[f] / (asum + 1e-6f);
        float sp, cp;
        __sincosf(phases[d], &sp, &cp);
        const float wv = lcu_w[f * Dd + d];
        s_tab[f * TABSTRIDE + 2 * d]     = sc * wv * cp;   // a_{d+1}
        s_tab[f * TABSTRIDE + 2 * d + 1] = -sc * wv * sp;  // b_{d+1}
        if (d == 0) s_tab[f * TABSTRIDE + 32] = K2 * sbias[f];
    }

    // ---- B fragments: wave wu owns classes [16wu,16wu+16) ----
    // MFMA step q, lane quarter h, regs j=0..7 hold phys kappa=(4q+h)*8+j,
    // i.e. f=4q+h, cheb-k=j (same lane<->k map on A and B => K-perm invariant)
    v8s Bfr[8];
    const int cidx = wu * 16 + r16;
#pragma unroll
    for (int q = 0; q < 8; ++q) {
        const int f = 4 * q + h;
        const float* gp = coeff + ((size_t)(cidx * F + f) * Kk);
        const float4 g0 = *reinterpret_cast<const float4*>(gp);
        const float4 g1 = *reinterpret_cast<const float4*>(gp + 4);
        union { unsigned u[4]; v8s v; } bb;
        bb.u[0] = cvtpk(g0.x, g0.y);
        bb.u[1] = cvtpk(g0.z, g0.w);
        bb.u[2] = cvtpk(g1.x, g1.y);
        bb.u[3] = cvtpk(g1.z, g1.w);
        Bfr[q] = bb.v;
    }
    const float biasreg = kbias[cidx];

    __syncthreads();  // table visible to all waves

    for (int mt = 0; mt < MT; ++mt) {
        const int row_base = rb0 + mt * 64;
        if (mt) __syncthreads();  // previous phase-2 reads done before overwrite

        // ---- phase 1: lane owns a row, wave owns features [8wu,8wu+8) ----
        {
            const float4 xa = mt ? xa1 : xa0;
            const float4 xb = mt ? xb1 : xb0;
            const float xv[8] = {xa.x, xa.y, xa.z, xa.w, xb.x, xb.y, xb.z, xb.w};
#pragma unroll
            for (int fl = 0; fl < 8; ++fl) {
                const int f = wu * 8 + fl;
                const float* tfp = s_tab + f * TABSTRIDE;
                const v2f* tf2 = reinterpret_cast<const v2f*>(tfp);  // wave-uniform addr
                const float fb = tfp[32];
                const float x = fminf(fmaxf(xv[fl], -CLIPV), CLIPV);
                const float s1 = sqrtf(fmaxf(__builtin_fmaf(-x, x, 1.f), 0.f));
                const float tx = x + x;
                const v2f tx2 = {tx, tx};
                // paired Clenshaw: .x = T-chain (coeff a), .y = U-chain (coeff b)
                v2f w = {0.f, 0.f}, wp = {0.f, 0.f};
#pragma unroll
                for (int j = 15; j >= 0; --j) {
                    const v2f wn = (tf2[j] - wp) + tx2 * w;  // v_pk_add + v_pk_fma
                    wp = w;
                    w = wn;
                }
                float z = fb - wp.x;                    // fb - u2
                z = __builtin_fmaf(x, w.x, z);          // + x*u1
                z = __builtin_fmaf(s1, w.y, z);         // + sqrt(1-x^2)*v1
                // tanh via exp2 (K2 pre-folded): t = 1 - 2/(2^z + 1)
                float e;
                asm("v_exp_f32 %0, %1" : "=v"(e) : "v"(z));
                const float rr = __builtin_amdgcn_rcpf(e + 1.f);
                const float t = __builtin_fmaf(-2.f, rr, 1.f);
                // Chebyshev basis T_0..T_7
                const float t2 = t + t;
                const float b1 = t;
                const float b2 = t2 * b1 - 1.f;
                const float b3 = t2 * b2 - b1;
                const float b4 = t2 * b3 - b2;
                const float b5 = t2 * b4 - b3;
                const float b6 = t2 * b5 - b4;
                const float b7 = t2 * b6 - b5;
                uint4 pk;
                pk.x = cvtpk(1.f, b1);
                pk.y = cvtpk(b2, b3);
                pk.z = cvtpk(b4, b5);
                pk.w = cvtpk(b6, b7);
                // conflict-free: 64 lanes write contiguous 1KB within chunk f
                *reinterpret_cast<uint4*>(&s_basis[f * CHUNKS + lane * 8]) = pk;
            }
        }
        __syncthreads();

        // ---- phase 2: MFMA, wave wu computes classes [16wu,16wu+16) for 64 rows ----
        {
#pragma unroll
            for (int t = 0; t < 4; ++t) {
                v4f acc = {0.f, 0.f, 0.f, 0.f};
#pragma unroll
                for (int q = 0; q < 8; ++q) {
                    const v8s a = *reinterpret_cast<const v8s*>(
                        &s_basis[(4 * q + h) * CHUNKS + (t * 16 + r16) * 8]);
                    acc = __builtin_amdgcn_mfma_f32_16x16x32_bf16(a, Bfr[q], acc, 0, 0, 0);
                }
                const int row0 = row_base + t * 16 + h * 4;
#pragma unroll
                for (int i = 0; i < 4; ++i) {
                    out[(size_t)(row0 + i) * C + cidx] = acc[i] + biasreg;
                }
            }
        }
    }
}

extern "C" void kernel_launch(void* const* d_in, const int* in_sizes, int n_in,
                              void* d_out, int out_size, void* d_ws, size_t ws_size,
                              hipStream_t stream) {
    const float* X  = (const float*)d_in[0];
    const float* ph = (const float*)d_in[1];
    const float* lw = (const float*)d_in[2];
    const float* ss = (const float*)d_in[3];
    const float* sb = (const float*)d_in[4];
    const float* kc = (const float*)d_in[5];
    const float* kb = (const float*)d_in[6];
    float* out = (float*)d_out;
    qkan_kernel<<<dim3(NBLK), dim3(256), 0, stream>>>(X, ph, lw, ss, sb, kc, kb, out);
}